// Round 11
// baseline (789.103 us; speedup 1.0000x reference)
//
#include <hip/hip_runtime.h>
#include <hip/hip_fp16.h>

#define N_NODES 50000
#define N_EDGES 800000
#define D 64
#define DHID 100
#define NTILES (N_NODES / 16)                   // 3125
#define NCT 7                                   // head col-tiles (112 cols padded)
#define CAP 32                                  // slots per node = ONE 128B csr line
#define SPILL_MAX 8192                          // overflow edges (exp ~20)
#define NBLK 1920                               // 7.5/CU needed; capacity 8/CU (margin 128)
#define NTHR 256
#define GSIZE (NBLK * NTHR)                     // 491520

typedef unsigned short ushort;
typedef unsigned int uint;
typedef __attribute__((ext_vector_type(8))) short s16x8;
typedef __attribute__((ext_vector_type(4))) float f32x4;

#define MFMA16(A, B, C) __builtin_amdgcn_mfma_f32_16x16x32_bf16((A), (B), (C), 0, 0, 0)

__device__ __forceinline__ float swishf(float x) { return x / (1.0f + __expf(-x)); }

__device__ __forceinline__ ushort f2bf(float f) {   // RTNE fp32 -> bf16
    uint u = __float_as_uint(f);
    uint r = (u + 0x7fffu + ((u >> 16) & 1u)) >> 16;
    return (ushort)r;
}
__device__ __forceinline__ float bf2f(ushort h) { return __uint_as_float((uint)h << 16); }
__device__ __forceinline__ float bf_lo(uint d) { return __uint_as_float(d << 16); }
__device__ __forceinline__ float bf_hi(uint d) { return __uint_as_float(d & 0xffff0000u); }

__device__ __forceinline__ float hwf(uint e) {
    return __half2float(__ushort_as_half((ushort)(e >> 16)));
}

__device__ __forceinline__ void accum8(float* acc, uint4 v, float w) {
    acc[0] = fmaf(w, bf_lo(v.x), acc[0]);
    acc[1] = fmaf(w, bf_hi(v.x), acc[1]);
    acc[2] = fmaf(w, bf_lo(v.y), acc[2]);
    acc[3] = fmaf(w, bf_hi(v.y), acc[3]);
    acc[4] = fmaf(w, bf_lo(v.z), acc[4]);
    acc[5] = fmaf(w, bf_hi(v.z), acc[5]);
    acc[6] = fmaf(w, bf_lo(v.w), acc[6]);
    acc[7] = fmaf(w, bf_hi(v.w), acc[7]);
}

// -------- software grid barrier (sense-reversal; proven correct in R10) --------
struct GBar { uint cnt; uint gen; };

__device__ __forceinline__ void gbar(GBar* b) {
    __syncthreads();
    if (threadIdx.x == 0) {
        __threadfence();             // release: flush this CU/XCD's caches
        uint g = atomicAdd(&b->gen, 0u);
        uint v = atomicAdd(&b->cnt, 1u) + 1;
        if (v == (uint)NBLK) {
            atomicAdd(&b->gen, 1u);
        } else {
            int t = 0;
            while (atomicAdd(&b->gen, 0u) == g) {
                __builtin_amdgcn_s_sleep(8);
                if (++t > 1000000) break;   // escape hatch: never hang
            }
        }
        __threadfence();             // acquire
    }
    __syncthreads();
}

// Gather body for one node (2 nodes per wave via half h). Bucket = ONE 128B
// line (CAP=32); eA/eB/degv loaded by caller in one issue window.
__device__ __forceinline__ void gather_body(const ushort* __restrict__ H,
                                            uint4 eA, uint4 eB, int degv,
                                            int j, int fg, float* acc) {
#pragma unroll
    for (int t = 0; t < 8; ++t) acc[t] = 0.f;
    const int sA = j * 4, sB = 16 + j * 4;
    bool pA = sA < degv, pB = sB < degv;
    uint4 vA0, vA1, vA2, vA3, vB0, vB1, vB2, vB3;
    float wA0 = 0, wA1 = 0, wA2 = 0, wA3 = 0;
    float wB0 = 0, wB1 = 0, wB2 = 0, wB3 = 0;
    if (pA) {
        wA0 = hwf(eA.x);
        wA1 = (sA + 1 < degv) ? hwf(eA.y) : 0.f;
        wA2 = (sA + 2 < degv) ? hwf(eA.z) : 0.f;
        wA3 = (sA + 3 < degv) ? hwf(eA.w) : 0.f;
        uint i0 = min(eA.x & 0xffffu, (uint)(N_NODES - 1));
        uint i1 = min(eA.y & 0xffffu, (uint)(N_NODES - 1));
        uint i2 = min(eA.z & 0xffffu, (uint)(N_NODES - 1));
        uint i3 = min(eA.w & 0xffffu, (uint)(N_NODES - 1));
        vA0 = *((const uint4*)(H + ((size_t)i0 << 6) + (fg << 3)));
        vA1 = *((const uint4*)(H + ((size_t)i1 << 6) + (fg << 3)));
        vA2 = *((const uint4*)(H + ((size_t)i2 << 6) + (fg << 3)));
        vA3 = *((const uint4*)(H + ((size_t)i3 << 6) + (fg << 3)));
    }
    if (pB) {
        wB0 = hwf(eB.x);
        wB1 = (sB + 1 < degv) ? hwf(eB.y) : 0.f;
        wB2 = (sB + 2 < degv) ? hwf(eB.z) : 0.f;
        wB3 = (sB + 3 < degv) ? hwf(eB.w) : 0.f;
        uint i0 = min(eB.x & 0xffffu, (uint)(N_NODES - 1));
        uint i1 = min(eB.y & 0xffffu, (uint)(N_NODES - 1));
        uint i2 = min(eB.z & 0xffffu, (uint)(N_NODES - 1));
        uint i3 = min(eB.w & 0xffffu, (uint)(N_NODES - 1));
        vB0 = *((const uint4*)(H + ((size_t)i0 << 6) + (fg << 3)));
        vB1 = *((const uint4*)(H + ((size_t)i1 << 6) + (fg << 3)));
        vB2 = *((const uint4*)(H + ((size_t)i2 << 6) + (fg << 3)));
        vB3 = *((const uint4*)(H + ((size_t)i3 << 6) + (fg << 3)));
    }
    if (pA) {
        accum8(acc, vA0, wA0);
        accum8(acc, vA1, wA1);
        accum8(acc, vA2, wA2);
        accum8(acc, vA3, wA3);
    }
    if (pB) {
        accum8(acc, vB0, wB0);
        accum8(acc, vB1, wB1);
        accum8(acc, vB2, wB2);
        accum8(acc, vB3, wB3);
    }
#pragma unroll
    for (int t = 0; t < 8; ++t) {
        acc[t] += __shfl_xor(acc[t], 8, 64);
        acc[t] += __shfl_xor(acc[t], 16, 64);
    }
}

__device__ __forceinline__ void add_spills(const ushort* __restrict__ H,
                                           const int* __restrict__ spillCnt,
                                           const uint2* __restrict__ spill,
                                           int node, int fg, float* acc) {
    int n = min(*spillCnt, SPILL_MAX);
    for (int i = 0; i < n; ++i) {
        uint2 sp = spill[i];
        if ((int)sp.x == node) {
            float wv = hwf(sp.y);
            uint si = min(sp.y & 0xffffu, (uint)(N_NODES - 1));
            uint4 v = *((const uint4*)(H + ((size_t)si << 6) + (fg << 3)));
            accum8(acc, v, wv);
        }
    }
}

// ======================= persistent mega-kernel, full-residency phases =======================
// P0: weight prep + L1 matmul (all blocks; most waves 1 tile)
// P1: csr fill — SINGLE PASS over edges (no groups), all 1920 blocks
// P2: layer-1 gather (+bias+swish) -> act1
// P3: layer-2 gather + W2 matmul + swish + MLP head -> out
__global__ __launch_bounds__(NTHR, 8) void mega(const int* __restrict__ src,
                                                const int* __restrict__ dst,
                                                const float* __restrict__ w,
                                                const float* __restrict__ X,
                                                const float* __restrict__ W1,
                                                const float* __restrict__ b1,
                                                const float* __restrict__ W2,
                                                const float* __restrict__ b2,
                                                const float* __restrict__ Wd,
                                                const float* __restrict__ bd,
                                                const float* __restrict__ Wo,
                                                const float* __restrict__ bo,
                                                float* __restrict__ out,
                                                int* __restrict__ deg,
                                                uint* __restrict__ csr,
                                                uint2* __restrict__ spill,
                                                ushort* __restrict__ H1,
                                                ushort* __restrict__ act1,
                                                short* __restrict__ W2T2,
                                                short* __restrict__ WdT2) {
    // 18432 B total LDS -> 8 blocks/CU. P3 aliases onto sBT.
    __shared__ __align__(16) short sBT[2][D][72];
    const int tid = threadIdx.x;
    const int bid = blockIdx.x;
    const int gtid = bid * NTHR + tid;
    int* spillCnt = deg + N_NODES;
    GBar* gb = (GBar*)(deg + N_NODES + 2);          // gb[0], gb[1] (zeroed by memset)

    // ---------------- P0: weight-split prep (global) ----------------
    for (int idx = gtid; idx < D * D; idx += GSIZE) {
        int k = idx >> 6, c = idx & 63;
        float wv = W2[idx];
        ushort hi = f2bf(wv);
        W2T2[(size_t)c * D + k] = (short)hi;
        W2T2[(size_t)(D + c) * D + k] = (short)f2bf(wv - bf2f(hi));
    }
    for (int idx = gtid; idx < NCT * 16 * D; idx += GSIZE) {
        int jj = idx >> 6, k = idx & 63;
        float wv = (jj < DHID) ? Wd[k * DHID + jj] : 0.f;
        ushort hi = f2bf(wv);
        WdT2[(size_t)jj * D + k] = (short)hi;
        WdT2[(size_t)(NCT * 16 + jj) * D + k] = (short)f2bf(wv - bf2f(hi));
    }

    // ---------------- P0b: H1 = X@W1 (all blocks; ~1 tile/wave) ----------------
    {
        for (int idx = tid; idx < D * D; idx += NTHR) {
            int k = idx >> 6, c = idx & 63;
            float wv = W1[idx];
            ushort hi = f2bf(wv);
            sBT[0][c][k] = (short)hi;
            sBT[1][c][k] = (short)f2bf(wv - bf2f(hi));
        }
        __syncthreads();
        int wv_ = tid >> 6, lane = tid & 63, quad = lane >> 4, m = lane & 15;
        for (int slot = bid * 4 + wv_; slot < NTILES; slot += NBLK * 4) {
            int node0 = slot * 16;
            f32x4 acc[4] = {{0,0,0,0},{0,0,0,0},{0,0,0,0},{0,0,0,0}};
#pragma unroll
            for (int kt = 0; kt < 2; ++kt) {
                int k0 = kt * 32 + quad * 8;
                const float* xp = X + ((size_t)(node0 + m) << 6) + k0;
                f32x4 xa = __builtin_nontemporal_load((const f32x4*)xp);
                f32x4 xb = __builtin_nontemporal_load((const f32x4*)(xp + 4));
                float xv[8] = {xa[0], xa[1], xa[2], xa[3], xb[0], xb[1], xb[2], xb[3]};
                s16x8 ahi, alo;
#pragma unroll
                for (int jj = 0; jj < 8; ++jj) {
                    ushort hi = f2bf(xv[jj]);
                    ahi[jj] = (short)hi;
                    alo[jj] = (short)f2bf(xv[jj] - bf2f(hi));
                }
#pragma unroll
                for (int ct = 0; ct < 4; ++ct) {
                    int n = ct * 16 + m;
                    s16x8 bhi = *((const s16x8*)&sBT[0][n][k0]);
                    s16x8 blo = *((const s16x8*)&sBT[1][n][k0]);
                    acc[ct] = MFMA16(ahi, bhi, acc[ct]);
                    acc[ct] = MFMA16(ahi, blo, acc[ct]);
                    acc[ct] = MFMA16(alo, bhi, acc[ct]);
                }
            }
            // direct C store (no LDS rep): row = node0+quad*4+r, col = ct*16+m
#pragma unroll
            for (int ct = 0; ct < 4; ++ct)
#pragma unroll
                for (int r = 0; r < 4; ++r)
                    H1[((size_t)(node0 + quad * 4 + r) << 6) + ct * 16 + m] =
                        (ushort)f2bf(acc[ct][r]);
        }
    }

    // ---------------- P1: fill — single pass, all blocks resident ----------------
    for (int e = gtid; e < N_EDGES; e += GSIZE) {
        int dv = __builtin_nontemporal_load(dst + e);    // read exactly once now
        float wval = __builtin_nontemporal_load(w + e);
        int sval = __builtin_nontemporal_load(src + e);
        uint hw = (uint)__half_as_ushort(__float2half_rn(wval));
        uint payload = (uint)sval | (hw << 16);
        int r = atomicAdd(&deg[dv], 1);
        if (r < CAP) {
            csr[(dv << 5) + r] = payload;
        } else {
            int si = atomicAdd(spillCnt, 1);
            if (si < SPILL_MAX) spill[si] = make_uint2((uint)dv, payload);
        }
    }
    gbar(&gb[0]);

    // ---------------- P2: layer-1 gather (+bias+swish) -> act1 ----------------
    {
        int wave = tid >> 6, lane = tid & 63;
        int h = lane >> 5, j = (lane >> 3) & 3, fg = lane & 7;
        for (int u = bid; u < N_NODES / 8; u += NBLK) {
            int node = u * 8 + wave * 2 + h;
            const uint* bucket = csr + ((size_t)node << 5);
            uint4 eA = *((const uint4*)(bucket + j * 4));
            uint4 eB = *((const uint4*)(bucket + 16 + j * 4));
            int degv = min(deg[node], CAP);
            float acc[8];
            gather_body(H1, eA, eB, degv, j, fg, acc);
            if (j == 0) {
                add_spills(H1, spillCnt, spill, node, fg, acc);
                float4 ba = ((const float4*)b1)[fg * 2];
                float4 bb = ((const float4*)b1)[fg * 2 + 1];
                float r0 = swishf(acc[0] + ba.x);
                float r1 = swishf(acc[1] + ba.y);
                float r2 = swishf(acc[2] + ba.z);
                float r3 = swishf(acc[3] + ba.w);
                float r4 = swishf(acc[4] + bb.x);
                float r5 = swishf(acc[5] + bb.y);
                float r6 = swishf(acc[6] + bb.z);
                float r7 = swishf(acc[7] + bb.w);
                uint4 u4;
                u4.x = (uint)f2bf(r0) | ((uint)f2bf(r1) << 16);
                u4.y = (uint)f2bf(r2) | ((uint)f2bf(r3) << 16);
                u4.z = (uint)f2bf(r4) | ((uint)f2bf(r5) << 16);
                u4.w = (uint)f2bf(r6) | ((uint)f2bf(r7) << 16);
                *((uint4*)(act1 + ((size_t)node << 6) + (fg << 3))) = u4;
            }
        }
    }
    gbar(&gb[1]);

    // ---------------- P3: layer-2 gather + W2 matmul + swish + head ----------------
    {
        char* smemB = (char*)&sBT[0][0][0];                   // alias (7168 B used)
        float (*sAgg)[72] = (float(*)[72])smemB;              // 4608 B
        short (*sAct2)[72] = (short(*)[72])(smemB + 4608);    // 2304 B
        float (*sPart)[16] = (float(*)[16])(smemB + 6912);    // 256 B
        int wv = tid >> 6, lane = tid & 63;
        int h = lane >> 5, j = (lane >> 3) & 3, fg = lane & 7;
        int quad = lane >> 4, m = lane & 15;
        for (int t = bid; t < NTILES; t += NBLK) {
            int node0 = t * 16;
            {
                int n0l = wv * 4 + h, n1l = wv * 4 + 2 + h;
                int n0 = node0 + n0l, n1 = node0 + n1l;
                const uint* bk0 = csr + ((size_t)n0 << 5);
                const uint* bk1 = csr + ((size_t)n1 << 5);
                uint4 eA0 = *((const uint4*)(bk0 + j * 4));
                uint4 eB0 = *((const uint4*)(bk0 + 16 + j * 4));
                uint4 eA1 = *((const uint4*)(bk1 + j * 4));
                uint4 eB1 = *((const uint4*)(bk1 + 16 + j * 4));
                int d0 = min(deg[n0], CAP);
                int d1 = min(deg[n1], CAP);
                float acc0[8];
                gather_body(act1, eA0, eB0, d0, j, fg, acc0);
                if (j == 0) {
                    add_spills(act1, spillCnt, spill, n0, fg, acc0);
                    float4 u0 = {acc0[0], acc0[1], acc0[2], acc0[3]};
                    float4 u1 = {acc0[4], acc0[5], acc0[6], acc0[7]};
                    *((float4*)&sAgg[n0l][fg * 8]) = u0;
                    *((float4*)&sAgg[n0l][fg * 8 + 4]) = u1;
                }
                float acc1[8];
                gather_body(act1, eA1, eB1, d1, j, fg, acc1);
                if (j == 0) {
                    add_spills(act1, spillCnt, spill, n1, fg, acc1);
                    float4 u0 = {acc1[0], acc1[1], acc1[2], acc1[3]};
                    float4 u1 = {acc1[4], acc1[5], acc1[6], acc1[7]};
                    *((float4*)&sAgg[n1l][fg * 8]) = u0;
                    *((float4*)&sAgg[n1l][fg * 8 + 4]) = u1;
                }
            }
            __syncthreads();

            {
                f32x4 acc = {0, 0, 0, 0};
                int n = wv * 16 + m;
#pragma unroll
                for (int kt = 0; kt < 2; ++kt) {
                    int k0 = kt * 32 + quad * 8;
                    float4 xa = *((const float4*)&sAgg[m][k0]);
                    float4 xb = *((const float4*)&sAgg[m][k0 + 4]);
                    float xv[8] = {xa.x, xa.y, xa.z, xa.w, xb.x, xb.y, xb.z, xb.w};
                    s16x8 ahi, alo;
#pragma unroll
                    for (int jj = 0; jj < 8; ++jj) {
                        ushort hi = f2bf(xv[jj]);
                        ahi[jj] = (short)hi;
                        alo[jj] = (short)f2bf(xv[jj] - bf2f(hi));
                    }
                    s16x8 bhi = *((const s16x8*)(W2T2 + (size_t)n * D + k0));
                    s16x8 blo = *((const s16x8*)(W2T2 + (size_t)(D + n) * D + k0));
                    acc = MFMA16(ahi, bhi, acc);
                    acc = MFMA16(ahi, blo, acc);
                    acc = MFMA16(alo, bhi, acc);
                }
                float bv = b2[n];
#pragma unroll
                for (int r = 0; r < 4; ++r)
                    sAct2[quad * 4 + r][n] = (short)f2bf(swishf(acc[r] + bv));
            }
            __syncthreads();

            float part[4] = {0, 0, 0, 0};
#pragma unroll
            for (int cc = 0; cc < 2; ++cc) {
                int ct = wv + cc * 4;
                if (ct < NCT) {
                    f32x4 acc = {0, 0, 0, 0};
                    int n = ct * 16 + m;
#pragma unroll
                    for (int kt = 0; kt < 2; ++kt) {
                        int k0 = kt * 32 + quad * 8;
                        s16x8 a = *((const s16x8*)&sAct2[m][k0]);
                        s16x8 bhi = *((const s16x8*)(WdT2 + (size_t)n * D + k0));
                        s16x8 blo = *((const s16x8*)(WdT2 + (size_t)(NCT * 16 + n) * D + k0));
                        acc = MFMA16(a, bhi, acc);
                        acc = MFMA16(a, blo, acc);
                    }
                    float bdv = (n < DHID) ? bd[n] : 0.f;
                    float wov = (n < DHID) ? Wo[n] : 0.f;
#pragma unroll
                    for (int r = 0; r < 4; ++r)
                        part[r] = fmaf(swishf(acc[r] + bdv), wov, part[r]);
                }
            }
#pragma unroll
            for (int r = 0; r < 4; ++r) {
                part[r] += __shfl_xor(part[r], 1, 64);
                part[r] += __shfl_xor(part[r], 2, 64);
                part[r] += __shfl_xor(part[r], 4, 64);
                part[r] += __shfl_xor(part[r], 8, 64);
            }
            if (m == 0) {
#pragma unroll
                for (int r = 0; r < 4; ++r)
                    sPart[wv][quad * 4 + r] = part[r];
            }
            __syncthreads();
            if (tid < 16) {
                float z = sPart[0][tid] + sPart[1][tid] + sPart[2][tid] + sPart[3][tid] + bo[0];
                out[node0 + tid] = 1.f / (1.f + __expf(-z));
            }
            __syncthreads();   // protect LDS reuse next tile
        }
    }
}

extern "C" void kernel_launch(void* const* d_in, const int* in_sizes, int n_in,
                              void* d_out, int out_size, void* d_ws, size_t ws_size,
                              hipStream_t stream) {
    const float* x   = (const float*)d_in[0];
    const int* esrc  = (const int*)d_in[1];
    const int* edst  = (const int*)d_in[2];
    const float* ew  = (const float*)d_in[3];
    const float* W1  = (const float*)d_in[4];
    const float* b1  = (const float*)d_in[5];
    const float* W2  = (const float*)d_in[6];
    const float* b2  = (const float*)d_in[7];
    const float* Wd  = (const float*)d_in[8];
    const float* bd  = (const float*)d_in[9];
    const float* Wo  = (const float*)d_in[10];
    const float* bo  = (const float*)d_in[11];
    float* out = (float*)d_out;

    char* ws = (char*)d_ws;
    ushort* H1    = (ushort*)ws; ws += (size_t)N_NODES * D * sizeof(ushort);   // 6.4 MB
    ushort* act1  = (ushort*)ws; ws += (size_t)N_NODES * D * sizeof(ushort);   // 6.4 MB
    uint* csr     = (uint*)ws;   ws += (size_t)N_NODES * CAP * sizeof(uint);   // 6.4 MB (not zeroed)
    int* deg      = (int*)ws;    ws += (size_t)(N_NODES + 8) * sizeof(int);    // deg + spillCnt + gbars
    uint2* spill  = (uint2*)ws;  ws += (size_t)SPILL_MAX * sizeof(uint2);      // 64 KB (not zeroed)
    short* W2T2   = (short*)ws;  ws += (size_t)2 * D * D * sizeof(short);      // 16 KB
    short* WdT2   = (short*)ws;  ws += (size_t)2 * NCT * 16 * D * sizeof(short); // 28.7 KB

    // ---- zero deg + spillCnt + barrier structs (one memset, replay-safe) ----
    hipMemsetAsync(deg, 0, (size_t)(N_NODES + 8) * sizeof(int), stream);

    // ---- single persistent mega-kernel (normal launch -> capture-safe) ----
    mega<<<NBLK, NTHR, 0, stream>>>(esrc, edst, ew, x, W1, b1, W2, b2, Wd, bd,
                                    Wo, bo, out, deg, csr, spill, H1, act1,
                                    W2T2, WdT2);
}

// Round 12
// 179.924 us; speedup vs baseline: 4.3858x; 4.3858x over previous
//
#include <hip/hip_runtime.h>
#include <hip/hip_fp16.h>

#define N_NODES 50000
#define N_EDGES 800000
#define D 64
#define DHID 100
#define NTILES (N_NODES / 16)                   // 3125
#define NCT 7                                   // head col-tiles (112 cols padded)
#define CAP 32                                  // slots per node = ONE 128B csr line
#define SPILL_MAX 8192                          // overflow edges (exp ~20)
#define NGROUPS 4                               // dst-range groups
#define NSLICES 780                             // fill blocks per group
#define FILL_BLOCKS (NGROUPS * NSLICES)         // 3120
#define MM_BLOCKS ((NTILES + 3) / 4)            // 782
#define DST_PER_GROUP (N_NODES / NGROUPS)       // 12500
#define FSTRIDE (NSLICES * 256)                 // 199680
#define KMAX 5                                  // scan iterations per thread

typedef unsigned short ushort;
typedef unsigned int uint;
typedef __attribute__((ext_vector_type(8))) short s16x8;
typedef __attribute__((ext_vector_type(4))) float f32x4;

#define MFMA16(A, B, C) __builtin_amdgcn_mfma_f32_16x16x32_bf16((A), (B), (C), 0, 0, 0)

__device__ __forceinline__ float swishf(float x) { return x / (1.0f + __expf(-x)); }

__device__ __forceinline__ ushort f2bf(float f) {   // RTNE fp32 -> bf16
    uint u = __float_as_uint(f);
    uint r = (u + 0x7fffu + ((u >> 16) & 1u)) >> 16;
    return (ushort)r;
}
__device__ __forceinline__ float bf2f(ushort h) { return __uint_as_float((uint)h << 16); }
__device__ __forceinline__ float bf_lo(uint d) { return __uint_as_float(d << 16); }
__device__ __forceinline__ float bf_hi(uint d) { return __uint_as_float(d & 0xffff0000u); }

__device__ __forceinline__ float hwf(uint e) {
    return __half2float(__ushort_as_half((ushort)(e >> 16)));
}

__device__ __forceinline__ void accum8(float* acc, uint4 v, float w) {
    acc[0] = fmaf(w, bf_lo(v.x), acc[0]);
    acc[1] = fmaf(w, bf_hi(v.x), acc[1]);
    acc[2] = fmaf(w, bf_lo(v.y), acc[2]);
    acc[3] = fmaf(w, bf_hi(v.y), acc[3]);
    acc[4] = fmaf(w, bf_lo(v.z), acc[4]);
    acc[5] = fmaf(w, bf_hi(v.z), acc[5]);
    acc[6] = fmaf(w, bf_lo(v.w), acc[6]);
    acc[7] = fmaf(w, bf_hi(v.w), acc[7]);
}

// Gather body for one node (2 nodes per wave, half h owns one node).
// Bucket is ONE 128B line (CAP=32): grain A = slots j*4.., grain B = 16+j*4..
// eA/eB/degv are loaded by the caller so both grains + deg issue in one window.
// Slot >= CAP edges are handled by the spill pass (add_spills).
__device__ __forceinline__ void gather_body(const ushort* __restrict__ H,
                                            uint4 eA, uint4 eB, int degv,
                                            int j, int fg, float* acc) {
#pragma unroll
    for (int t = 0; t < 8; ++t) acc[t] = 0.f;
    const int sA = j * 4, sB = 16 + j * 4;
    bool pA = sA < degv, pB = sB < degv;
    uint4 vA0, vA1, vA2, vA3, vB0, vB1, vB2, vB3;
    float wA0 = 0, wA1 = 0, wA2 = 0, wA3 = 0;
    float wB0 = 0, wB1 = 0, wB2 = 0, wB3 = 0;
    if (pA) {                                        // issue A row loads
        wA0 = hwf(eA.x);
        wA1 = (sA + 1 < degv) ? hwf(eA.y) : 0.f;
        wA2 = (sA + 2 < degv) ? hwf(eA.z) : 0.f;
        wA3 = (sA + 3 < degv) ? hwf(eA.w) : 0.f;
        uint i0 = min(eA.x & 0xffffu, (uint)(N_NODES - 1));
        uint i1 = min(eA.y & 0xffffu, (uint)(N_NODES - 1));
        uint i2 = min(eA.z & 0xffffu, (uint)(N_NODES - 1));
        uint i3 = min(eA.w & 0xffffu, (uint)(N_NODES - 1));
        vA0 = *((const uint4*)(H + ((size_t)i0 << 6) + (fg << 3)));
        vA1 = *((const uint4*)(H + ((size_t)i1 << 6) + (fg << 3)));
        vA2 = *((const uint4*)(H + ((size_t)i2 << 6) + (fg << 3)));
        vA3 = *((const uint4*)(H + ((size_t)i3 << 6) + (fg << 3)));
    }
    if (pB) {                                        // issue B row loads before A's FMAs
        wB0 = hwf(eB.x);
        wB1 = (sB + 1 < degv) ? hwf(eB.y) : 0.f;
        wB2 = (sB + 2 < degv) ? hwf(eB.z) : 0.f;
        wB3 = (sB + 3 < degv) ? hwf(eB.w) : 0.f;
        uint i0 = min(eB.x & 0xffffu, (uint)(N_NODES - 1));
        uint i1 = min(eB.y & 0xffffu, (uint)(N_NODES - 1));
        uint i2 = min(eB.z & 0xffffu, (uint)(N_NODES - 1));
        uint i3 = min(eB.w & 0xffffu, (uint)(N_NODES - 1));
        vB0 = *((const uint4*)(H + ((size_t)i0 << 6) + (fg << 3)));
        vB1 = *((const uint4*)(H + ((size_t)i1 << 6) + (fg << 3)));
        vB2 = *((const uint4*)(H + ((size_t)i2 << 6) + (fg << 3)));
        vB3 = *((const uint4*)(H + ((size_t)i3 << 6) + (fg << 3)));
    }
    if (pA) {
        accum8(acc, vA0, wA0);
        accum8(acc, vA1, wA1);
        accum8(acc, vA2, wA2);
        accum8(acc, vA3, wA3);
    }
    if (pB) {
        accum8(acc, vB0, wB0);
        accum8(acc, vB1, wB1);
        accum8(acc, vB2, wB2);
        accum8(acc, vB3, wB3);
    }
    // reduce over the 4 quads of each 32-lane half (xor 8,16 stay in-half)
#pragma unroll
    for (int t = 0; t < 8; ++t) {
        acc[t] += __shfl_xor(acc[t], 8, 64);
        acc[t] += __shfl_xor(acc[t], 16, 64);
    }
}

// Overflow edges (slot >= CAP in fill). Runs on j==0 lanes AFTER the reduce:
// acc holds the node's full partial sum, add each matching spill edge.
// Expected nspill ~ 20 for the whole graph; list is L2-hot.
__device__ __forceinline__ void add_spills(const ushort* __restrict__ H,
                                           const int* __restrict__ spillCnt,
                                           const uint2* __restrict__ spill,
                                           int node, int fg, float* acc) {
    int n = min(*spillCnt, SPILL_MAX);
    for (int i = 0; i < n; ++i) {
        uint2 sp = spill[i];
        if ((int)sp.x == node) {
            float wv = hwf(sp.y);
            uint si = min(sp.y & 0xffffu, (uint)(N_NODES - 1));
            uint4 v = *((const uint4*)(H + ((size_t)si << 6) + (fg << 3)));
            accum8(acc, v, wv);
        }
    }
}

// ---- fused: XCD-partitioned fill + H1 = X@W1 + weight-split prep (2 blocks) ----
__global__ __launch_bounds__(256) void fill_and_l1(const int* __restrict__ src,
                                                   const int* __restrict__ dst,
                                                   const float* __restrict__ w,
                                                   int* __restrict__ deg,
                                                   uint* __restrict__ csr,
                                                   int* __restrict__ spillCnt,
                                                   uint2* __restrict__ spill,
                                                   const float* __restrict__ X,
                                                   const float* __restrict__ W,
                                                   const float* __restrict__ W2,
                                                   const float* __restrict__ Wd,
                                                   short* __restrict__ W2T2,
                                                   short* __restrict__ WdT2,
                                                   ushort* __restrict__ H) {
    __shared__ __align__(16) short sBT[2][D][72];    // 18.4 KB (aliased as rep later)
    int tid = threadIdx.x;

    if (blockIdx.x < FILL_BLOCKS) {
        // CAP=32: each node's bucket is ONE 128B line; a group's csr slab is
        // 1.6 MB -> stays L2-resident for the whole scan (no mid-kernel
        // partial-dirty eviction churn). dst CACHED (re-scanned 4x,
        // L2/L3-absorbed); src/w NT (read-once, keep them out of L2 so the
        // hot csr lines stay resident). Slot>=32 -> tiny global spill list.
        const int g = blockIdx.x & (NGROUPS - 1);
        const int s = blockIdx.x >> 2;               // slice 0..NSLICES-1
        const int lo = g * DST_PER_GROUP;
        const int e0 = s * 256 + tid;
        int d[KMAX];
        bool mk[KMAX];
#pragma unroll
        for (int k = 0; k < KMAX; ++k) {
            int e = e0 + k * FSTRIDE;
            int dv = (e < N_EDGES) ? dst[e] : -1;
            d[k] = dv;
            mk[k] = ((uint)(dv - lo) < (uint)DST_PER_GROUP);
        }
        float wv5[KMAX];
        int sv5[KMAX];
#pragma unroll
        for (int k = 0; k < KMAX; ++k)
            if (mk[k]) {
                int e = e0 + k * FSTRIDE;
                wv5[k] = __builtin_nontemporal_load(w + e);
                sv5[k] = __builtin_nontemporal_load(src + e);
            }
        int r5[KMAX];
#pragma unroll
        for (int k = 0; k < KMAX; ++k)
            if (mk[k]) r5[k] = atomicAdd(&deg[d[k]], 1);
#pragma unroll
        for (int k = 0; k < KMAX; ++k)
            if (mk[k]) {
                uint hw = (uint)__half_as_ushort(__float2half_rn(wv5[k]));
                uint payload = (uint)sv5[k] | (hw << 16);
                int r = r5[k];
                if (r < CAP) {
                    csr[(d[k] << 5) + r] = payload;
                } else {
                    int si = atomicAdd(spillCnt, 1);
                    if (si < SPILL_MAX) spill[si] = make_uint2((uint)d[k], payload);
                }
            }
        return;
    }

    if (blockIdx.x >= FILL_BLOCKS + MM_BLOCKS) {
        // ---------- weight-split prep ----------
        if (blockIdx.x == FILL_BLOCKS + MM_BLOCKS) {
            for (int idx = tid; idx < D * D; idx += 256) {
                int k = idx >> 6, c = idx & 63;
                float wv = W2[idx];
                ushort hi = f2bf(wv);
                W2T2[(size_t)c * D + k] = (short)hi;
                W2T2[(size_t)(D + c) * D + k] = (short)f2bf(wv - bf2f(hi));
            }
        } else {
            for (int idx = tid; idx < NCT * 16 * D; idx += 256) {
                int jj = idx >> 6, k = idx & 63;
                float wv = (jj < DHID) ? Wd[k * DHID + jj] : 0.f;
                ushort hi = f2bf(wv);
                WdT2[(size_t)jj * D + k] = (short)hi;
                WdT2[(size_t)(NCT * 16 + jj) * D + k] = (short)f2bf(wv - bf2f(hi));
            }
        }
        return;
    }

    // ---------- mfma_l1 path ----------
    for (int idx = tid; idx < D * D; idx += 256) {
        int k = idx >> 6, c = idx & 63;
        float wv = W[idx];
        ushort hi = f2bf(wv);
        sBT[0][c][k] = (short)hi;
        sBT[1][c][k] = (short)f2bf(wv - bf2f(hi));
    }
    __syncthreads();
    int wv_ = tid >> 6, lane = tid & 63, quad = lane >> 4, m = lane & 15;
    int tile = min((blockIdx.x - FILL_BLOCKS) * 4 + wv_, NTILES - 1);  // clamp (dup stores ok)
    int node0 = tile * 16;

    f32x4 acc[4] = {{0,0,0,0},{0,0,0,0},{0,0,0,0},{0,0,0,0}};
#pragma unroll
    for (int kt = 0; kt < 2; ++kt) {
        int k0 = kt * 32 + quad * 8;
        const float* xp = X + ((size_t)(node0 + m) << 6) + k0;
        f32x4 xa = __builtin_nontemporal_load((const f32x4*)xp);   // NT: X read-once
        f32x4 xb = __builtin_nontemporal_load((const f32x4*)(xp + 4));
        float xv[8] = {xa[0], xa[1], xa[2], xa[3], xb[0], xb[1], xb[2], xb[3]};
        s16x8 ahi, alo;
#pragma unroll
        for (int jj = 0; jj < 8; ++jj) {
            ushort hi = f2bf(xv[jj]);
            ahi[jj] = (short)hi;
            alo[jj] = (short)f2bf(xv[jj] - bf2f(hi));
        }
#pragma unroll
        for (int ct = 0; ct < 4; ++ct) {
            int n = ct * 16 + m;
            s16x8 bhi = *((const s16x8*)&sBT[0][n][k0]);
            s16x8 blo = *((const s16x8*)&sBT[1][n][k0]);
            acc[ct] = MFMA16(ahi, bhi, acc[ct]);
            acc[ct] = MFMA16(ahi, blo, acc[ct]);
            acc[ct] = MFMA16(alo, bhi, acc[ct]);
        }
    }
    __syncthreads();   // safe to alias rep over sBT
    short (*rep)[16][72] = (short(*)[16][72])&sBT[0][0][0];
#pragma unroll
    for (int ct = 0; ct < 4; ++ct)
#pragma unroll
        for (int r = 0; r < 4; ++r)
            rep[wv_][quad * 4 + r][ct * 16 + m] = (short)f2bf(acc[ct][r]);
#pragma unroll
    for (int half = 0; half < 2; ++half) {
        int r = (lane >> 3) + half * 8;
        int c0 = (lane & 7) * 8;
        s16x8 v = *((const s16x8*)&rep[wv_][r][c0]);
        *((s16x8*)(H + ((size_t)(node0 + r) << 6) + c0)) = v;
    }
}

// ---------------- gather + bias + swish -> bf16 activation (layer 1) ----------------
// 2 nodes per wave: 8 nodes per 256-thread block, full grid (R1-best config).
__global__ __launch_bounds__(256) void gather_act(const ushort* __restrict__ H,
                                                  const int* __restrict__ deg,
                                                  const uint* __restrict__ csr,
                                                  const int* __restrict__ spillCnt,
                                                  const uint2* __restrict__ spill,
                                                  const float* __restrict__ bias,
                                                  ushort* __restrict__ actOut) {
    int tid = threadIdx.x;
    int wave = tid >> 6, lane = tid & 63;
    int h = lane >> 5, j = (lane >> 3) & 3, fg = lane & 7;
    int node = blockIdx.x * 8 + wave * 2 + h;
    const uint* bucket = csr + ((size_t)node << 5);
    uint4 eA = *((const uint4*)(bucket + j * 4));        // same 128B line
    uint4 eB = *((const uint4*)(bucket + 16 + j * 4));
    int degv = min(deg[node], CAP);

    float acc[8];
    gather_body(H, eA, eB, degv, j, fg, acc);
    if (j == 0) {
        add_spills(H, spillCnt, spill, node, fg, acc);
        float4 ba = ((const float4*)bias)[fg * 2];
        float4 bb = ((const float4*)bias)[fg * 2 + 1];
        float r0 = swishf(acc[0] + ba.x);
        float r1 = swishf(acc[1] + ba.y);
        float r2 = swishf(acc[2] + ba.z);
        float r3 = swishf(acc[3] + ba.w);
        float r4 = swishf(acc[4] + bb.x);
        float r5 = swishf(acc[5] + bb.y);
        float r6 = swishf(acc[6] + bb.z);
        float r7 = swishf(acc[7] + bb.w);
        uint4 u;
        u.x = (uint)f2bf(r0) | ((uint)f2bf(r1) << 16);
        u.y = (uint)f2bf(r2) | ((uint)f2bf(r3) << 16);
        u.z = (uint)f2bf(r4) | ((uint)f2bf(r5) << 16);
        u.w = (uint)f2bf(r6) | ((uint)f2bf(r7) << 16);
        *((uint4*)(actOut + ((size_t)node << 6) + (fg << 3))) = u;
    }
}

// ---- fused: layer-2 gather + W2 matmul + bias + swish + MLP head, one 16-node tile/block ----
__global__ __launch_bounds__(256) void gather_tail(const ushort* __restrict__ act1,
                                                   const int* __restrict__ deg,
                                                   const uint* __restrict__ csr,
                                                   const int* __restrict__ spillCnt,
                                                   const uint2* __restrict__ spill,
                                                   const short* __restrict__ W2T2,
                                                   const float* __restrict__ b2,
                                                   const short* __restrict__ WdT2,
                                                   const float* __restrict__ bd,
                                                   const float* __restrict__ Wo,
                                                   const float* __restrict__ bo,
                                                   float* __restrict__ out) {
    __shared__ __align__(16) float sAgg[16][72];    // 4.6 KB fp32 aggregates
    __shared__ __align__(16) short sAct2[16][72];   // 2.3 KB bf16 act2 tile
    __shared__ float sPart[4][16];                  // per-wave head partials
    int tid = threadIdx.x;
    int wv = tid >> 6, lane = tid & 63;
    int h = lane >> 5, j = (lane >> 3) & 3, fg = lane & 7;
    int quad = lane >> 4, m = lane & 15;
    int node0 = blockIdx.x * 16;

    // ---- phase 0: gather 4 nodes per wave, both passes' bucket+deg up-front ----
    {
        int n0l = wv * 4 + h, n1l = wv * 4 + 2 + h;
        int n0 = node0 + n0l, n1 = node0 + n1l;
        const uint* b0 = csr + ((size_t)n0 << 5);
        const uint* b1 = csr + ((size_t)n1 << 5);
        uint4 eA0 = *((const uint4*)(b0 + j * 4));
        uint4 eB0 = *((const uint4*)(b0 + 16 + j * 4));
        uint4 eA1 = *((const uint4*)(b1 + j * 4));
        uint4 eB1 = *((const uint4*)(b1 + 16 + j * 4));
        int d0 = min(deg[n0], CAP);
        int d1 = min(deg[n1], CAP);

        float acc0[8];
        gather_body(act1, eA0, eB0, d0, j, fg, acc0);
        if (j == 0) {
            add_spills(act1, spillCnt, spill, n0, fg, acc0);
            float4 u0 = {acc0[0], acc0[1], acc0[2], acc0[3]};
            float4 u1 = {acc0[4], acc0[5], acc0[6], acc0[7]};
            *((float4*)&sAgg[n0l][fg * 8]) = u0;
            *((float4*)&sAgg[n0l][fg * 8 + 4]) = u1;
        }
        float acc1[8];
        gather_body(act1, eA1, eB1, d1, j, fg, acc1);
        if (j == 0) {
            add_spills(act1, spillCnt, spill, n1, fg, acc1);
            float4 u0 = {acc1[0], acc1[1], acc1[2], acc1[3]};
            float4 u1 = {acc1[4], acc1[5], acc1[6], acc1[7]};
            *((float4*)&sAgg[n1l][fg * 8]) = u0;
            *((float4*)&sAgg[n1l][fg * 8 + 4]) = u1;
        }
    }
    __syncthreads();

    // ---- phase A: act2 = swish(agg @ W2 + b2), wave wv -> col-tile wv ----
    {
        f32x4 acc = {0, 0, 0, 0};
        int n = wv * 16 + m;
#pragma unroll
        for (int kt = 0; kt < 2; ++kt) {
            int k0 = kt * 32 + quad * 8;
            float4 xa = *((const float4*)&sAgg[m][k0]);
            float4 xb = *((const float4*)&sAgg[m][k0 + 4]);
            float xv[8] = {xa.x, xa.y, xa.z, xa.w, xb.x, xb.y, xb.z, xb.w};
            s16x8 ahi, alo;
#pragma unroll
            for (int jj = 0; jj < 8; ++jj) {
                ushort hi = f2bf(xv[jj]);
                ahi[jj] = (short)hi;
                alo[jj] = (short)f2bf(xv[jj] - bf2f(hi));
            }
            s16x8 bhi = *((const s16x8*)(W2T2 + (size_t)n * D + k0));
            s16x8 blo = *((const s16x8*)(W2T2 + (size_t)(D + n) * D + k0));
            acc = MFMA16(ahi, bhi, acc);
            acc = MFMA16(ahi, blo, acc);
            acc = MFMA16(alo, bhi, acc);
        }
        float bv = b2[n];
#pragma unroll
        for (int r = 0; r < 4; ++r)
            sAct2[quad * 4 + r][n] = (short)f2bf(swishf(acc[r] + bv));
    }
    __syncthreads();

    // ---- phase B: head over col-tiles {wv, wv+4} ----
    float part[4] = {0, 0, 0, 0};
#pragma unroll
    for (int cc = 0; cc < 2; ++cc) {
        int ct = wv + cc * 4;
        if (ct < NCT) {
            f32x4 acc = {0, 0, 0, 0};
            int n = ct * 16 + m;
#pragma unroll
            for (int kt = 0; kt < 2; ++kt) {
                int k0 = kt * 32 + quad * 8;
                s16x8 a = *((const s16x8*)&sAct2[m][k0]);
                s16x8 bhi = *((const s16x8*)(WdT2 + (size_t)n * D + k0));
                s16x8 blo = *((const s16x8*)(WdT2 + (size_t)(NCT * 16 + n) * D + k0));
                acc = MFMA16(a, bhi, acc);
                acc = MFMA16(a, blo, acc);
            }
            float bdv = (n < DHID) ? bd[n] : 0.f;
            float wov = (n < DHID) ? Wo[n] : 0.f;
#pragma unroll
            for (int r = 0; r < 4; ++r)
                part[r] = fmaf(swishf(acc[r] + bdv), wov, part[r]);
        }
    }
#pragma unroll
    for (int r = 0; r < 4; ++r) {
        part[r] += __shfl_xor(part[r], 1, 64);
        part[r] += __shfl_xor(part[r], 2, 64);
        part[r] += __shfl_xor(part[r], 4, 64);
        part[r] += __shfl_xor(part[r], 8, 64);
    }
    if (m == 0) {
#pragma unroll
        for (int r = 0; r < 4; ++r)
            sPart[wv][quad * 4 + r] = part[r];
    }
    __syncthreads();
    if (tid < 16) {
        float z = sPart[0][tid] + sPart[1][tid] + sPart[2][tid] + sPart[3][tid] + bo[0];
        out[node0 + tid] = 1.f / (1.f + __expf(-z));
    }
}

extern "C" void kernel_launch(void* const* d_in, const int* in_sizes, int n_in,
                              void* d_out, int out_size, void* d_ws, size_t ws_size,
                              hipStream_t stream) {
    const float* x   = (const float*)d_in[0];
    const int* esrc  = (const int*)d_in[1];
    const int* edst  = (const int*)d_in[2];
    const float* ew  = (const float*)d_in[3];
    const float* W1  = (const float*)d_in[4];
    const float* b1  = (const float*)d_in[5];
    const float* W2  = (const float*)d_in[6];
    const float* b2  = (const float*)d_in[7];
    const float* Wd  = (const float*)d_in[8];
    const float* bd  = (const float*)d_in[9];
    const float* Wo  = (const float*)d_in[10];
    const float* bo  = (const float*)d_in[11];
    float* out = (float*)d_out;

    char* ws = (char*)d_ws;
    ushort* H1    = (ushort*)ws; ws += (size_t)N_NODES * D * sizeof(ushort);   // 6.4 MB
    ushort* act1  = (ushort*)ws; ws += (size_t)N_NODES * D * sizeof(ushort);   // 6.4 MB
    uint* csr     = (uint*)ws;   ws += (size_t)N_NODES * CAP * sizeof(uint);   // 6.4 MB (not zeroed)
    int* deg      = (int*)ws;    ws += (size_t)N_NODES * sizeof(int);          // 200 KB
    int* spillCnt = (int*)ws;    ws += 4 * sizeof(int);                        // adj. to deg
    uint2* spill  = (uint2*)ws;  ws += (size_t)SPILL_MAX * sizeof(uint2);      // 64 KB (not zeroed)
    short* W2T2   = (short*)ws;  ws += (size_t)2 * D * D * sizeof(short);      // 16 KB
    short* WdT2   = (short*)ws;  ws += (size_t)2 * NCT * 16 * D * sizeof(short); // 28.7 KB

    const int gBlocks = N_NODES / 8;   // 6250 (2 nodes per wave, full grid)

    // ---- zero deg + spillCnt in one memset (contiguous) ----
    hipMemsetAsync(deg, 0, (size_t)(N_NODES + 4) * sizeof(int), stream);

    // ---- fused: XCD-partitioned fill + layer-1 matmul + weight prep ----
    fill_and_l1<<<FILL_BLOCKS + MM_BLOCKS + 2, 256, 0, stream>>>(
        esrc, edst, ew, deg, csr, spillCnt, spill, x, W1, W2, Wd, W2T2, WdT2, H1);

    // ---- layer 1 gather (+bias+swish) ----
    gather_act<<<gBlocks, 256, 0, stream>>>(H1, deg, csr, spillCnt, spill, b1, act1);

    // ---- fused: layer-2 gather + W2 matmul + swish + MLP head ----
    gather_tail<<<NTILES, 256, 0, stream>>>(act1, deg, csr, spillCnt, spill,
                                            W2T2, b2, WdT2, bd, Wo, bo, out);
}